// Round 8
// baseline (347.054 us; speedup 1.0000x reference)
//
#include <hip/hip_runtime.h>

#define NROWS 4096
#define NDOM 8

typedef short short8 __attribute__((ext_vector_type(8)));
typedef float floatx4 __attribute__((ext_vector_type(4)));
typedef unsigned short ushort8v __attribute__((ext_vector_type(8)));

__device__ __forceinline__ unsigned short f2bf(float f) {
    union { float f; unsigned u; } v; v.f = f;
    unsigned r = v.u + 0x7FFFu + ((v.u >> 16) & 1u);  // RNE
    return (unsigned short)(r >> 16);
}

// ---------------------------------------------------------------------------
// Fused precompute dispatch:
//   blocks [0,256)     : xb = bf16(x), original row order
//   blocks [256,768)   : w0t = bf16(sk0*dk0) transposed [d][n][k]
//   blocks [768,1024)  : w1t
//   blocks [1024,1088) : w2t
//   block 1088         : deterministic counting-sort -> offsets, rowidx
// Phase A now uses float4 loads along n (4 k-rows x 256B per instr) instead
// of scalar 4-B strided loads — that was the 2.4 TB/s limiter in R6/R7.
// ---------------------------------------------------------------------------

template <int K, int N>
__device__ __forceinline__ void weff_tile(const float* __restrict__ sk,
                                          const float* __restrict__ dk,
                                          unsigned short* __restrict__ wt,
                                          unsigned short* __restrict__ lds,
                                          int local) {
    const int d = local & 7;
    const int rest = local >> 3;
    const int k0 = (rest & (K / 256 - 1)) * 256;
    const int n0 = (rest / (K / 256)) * 64;
    const int t = threadIdx.x;

    // phase A: float4-vectorized read, LDS [n][k] with chunk-XOR swizzle
    const int q = t & 15;          // n-quad: n = n0 + q*4 .. +3
    const int kr = t >> 4;         // k-row within group of 16
    const int ke = kr & 7;         // element within 8-chunk
#pragma unroll
    for (int pass = 0; pass < 16; ++pass) {
        const int krel = pass * 16 + kr;        // 0..255
        const int k = k0 + krel;
        floatx4 s = *(const floatx4*)(sk + (size_t)k * N + n0 + q * 4);
        floatx4 dd = *(const floatx4*)(dk + ((size_t)d * K + k) * N + n0 + q * 4);
        const int ch = krel >> 3;
#pragma unroll
        for (int c = 0; c < 4; ++c) {
            int n = q * 4 + c;
            lds[n * 256 + (ch ^ (n & 31)) * 8 + ke] = f2bf(s[c] * dd[c]);
        }
    }
    __syncthreads();

    // phase B: read LDS along k, store global [n][k] coalesced (32B units)
#pragma unroll
    for (int it = 0; it < 4; ++it) {
        const int nn = (t >> 4) + it * 16;
        const int c = t & 15;
        ushort8v a = *(ushort8v*)&lds[nn * 256 + ((2 * c) ^ (nn & 31)) * 8];
        ushort8v b = *(ushort8v*)&lds[nn * 256 + ((2 * c + 1) ^ (nn & 31)) * 8];
        unsigned short* dst = wt + ((size_t)d * N + n0 + nn) * K + k0 + c * 16;
        *(ushort8v*)dst = a;
        *(ushort8v*)(dst + 8) = b;
    }
}

__global__ void precompute_kernel(const float* __restrict__ x,
                                  const int* __restrict__ ind,
                                  const float* __restrict__ sk0, const float* __restrict__ dk0,
                                  const float* __restrict__ sk1, const float* __restrict__ dk1,
                                  const float* __restrict__ sk2, const float* __restrict__ dk2,
                                  unsigned short* __restrict__ xb,
                                  unsigned short* __restrict__ w0t,
                                  unsigned short* __restrict__ w1t,
                                  unsigned short* __restrict__ w2t,
                                  int* __restrict__ offsets,
                                  int* __restrict__ rowidx) {
    __shared__ unsigned short wtile[64 * 256];
    __shared__ unsigned short cnt[256][NDOM];
    __shared__ int base[256][NDOM];
    __shared__ int dom_total[NDOM];
    __shared__ int dom_off[NDOM + 1];

    const int b = blockIdx.x;
    const int t = threadIdx.x;

    if (b < 256) {
#pragma unroll
        for (int pass = 0; pass < 8; ++pass) {
            int row = b * 16 + pass * 2 + (t >> 7);
            int ch = t & 127;
            const float* src = x + (size_t)row * 1024 + ch * 8;
            floatx4 v0 = *(const floatx4*)src;
            floatx4 v1 = *(const floatx4*)(src + 4);
            unsigned short o[8];
            o[0] = f2bf(v0[0]); o[1] = f2bf(v0[1]); o[2] = f2bf(v0[2]); o[3] = f2bf(v0[3]);
            o[4] = f2bf(v1[0]); o[5] = f2bf(v1[1]); o[6] = f2bf(v1[2]); o[7] = f2bf(v1[3]);
            *(ushort8v*)(xb + (size_t)row * 1024 + ch * 8) = *(ushort8v*)o;
        }
    } else if (b < 256 + 512) {
        weff_tile<1024, 1024>(sk0, dk0, w0t, wtile, b - 256);
    } else if (b < 256 + 512 + 256) {
        weff_tile<1024, 512>(sk1, dk1, w1t, wtile, b - (256 + 512));
    } else if (b < 256 + 512 + 256 + 64) {
        weff_tile<512, 256>(sk2, dk2, w2t, wtile, b - (256 + 512 + 256));
    } else {
        int myind[16];
#pragma unroll
        for (int i = 0; i < 16; ++i) myind[i] = ind[t * 16 + i];
        unsigned short c[NDOM];
#pragma unroll
        for (int d = 0; d < NDOM; ++d) c[d] = 0;
#pragma unroll
        for (int i = 0; i < 16; ++i) c[myind[i]]++;
#pragma unroll
        for (int d = 0; d < NDOM; ++d) cnt[t][d] = c[d];
        __syncthreads();
        if (t < NDOM) {
            int acc = 0;
            for (int ch = 0; ch < 256; ++ch) { base[ch][t] = acc; acc += cnt[ch][t]; }
            dom_total[t] = acc;
        }
        __syncthreads();
        if (t == 0) {
            int acc = 0;
            for (int d = 0; d < NDOM; ++d) { dom_off[d] = acc; acc += dom_total[d]; }
            dom_off[NDOM] = acc;
        }
        __syncthreads();
        int pos[NDOM];
#pragma unroll
        for (int d = 0; d < NDOM; ++d) pos[d] = dom_off[d] + base[t][d];
#pragma unroll
        for (int i = 0; i < 16; ++i) {
            int dm = myind[i];
            rowidx[pos[dm]++] = t * 16 + i;
        }
        if (t <= NDOM) offsets[t] = dom_off[t];
    }
}

// ---------------------------------------------------------------------------
// Grouped GEMM, direct-to-register, SMALL wave tiles + high occupancy.
// Wave tile 32x32 (FM=FN=2): acc 16 VGPR + 4-deep frag buffers 64 VGPR.
// __launch_bounds__(256,4) caps VGPR at 128 -> 4 waves/SIMD; grids sized for
// 8-16 waves/CU so vmcnt stalls overlap across waves (R7 had 1 wave/SIMD at
// 256 VGPR — that was the regression). All k-offsets fit the 13-bit imm, so
// the k-loop is pure imm-offset dwordx4 loads + MFMA, no barriers, no LDS.
// ---------------------------------------------------------------------------
template <int FM, int FN, int MSLOTS, int K, int N, bool GATHER, bool SCATTER>
__launch_bounds__(256, 4)
__global__ void star_gemm(const unsigned short* __restrict__ Ab,
                          const unsigned short* __restrict__ Wt,
                          const float* __restrict__ sb,
                          const float* __restrict__ db,
                          float* __restrict__ OutF,
                          unsigned short* __restrict__ OutB,
                          const int* __restrict__ offsets,
                          const int* __restrict__ rowidx) {
    constexpr int TM = FM * 16;
    constexpr int TN = FN * 16;
    constexpr int NS = K / 32;                  // 32-wide k steps
    constexpr int DEPTH = 4;                    // NS % DEPTH == 0

    const int gid = blockIdx.x;
    const int w = threadIdx.x >> 6;
    const int lane = threadIdx.x & 63;
    const int lm = lane & 15;
    const int quad = lane >> 4;

    const int d = gid & 7;                      // domain -> XCD round-robin
    const int rest = (gid >> 3) * 4 + w;        // independent wave tile id
    const int mslot = rest % MSLOTS;
    const int n0 = (rest / MSLOTS) * TN;

    const int bstart = offsets[d];
    const int bend = offsets[d + 1];
    const int bsize = bend - bstart;

    float bias[FN];
    const unsigned short* wp[FN];
#pragma unroll
    for (int j = 0; j < FN; ++j) {
        int n = n0 + j * 16 + lm;
        bias[j] = sb[n] + db[d * N + n];
        wp[j] = Wt + ((size_t)d * N + n) * K + quad * 8;
    }

    for (int mt = mslot; mt * TM < bsize; mt += MSLOTS) {
        const int row_start = bstart + mt * TM;

        const unsigned short* ap[FM];
#pragma unroll
        for (int i = 0; i < FM; ++i) {
            int p = row_start + i * 16 + lm;
            if (p >= bend) p = bend - 1;        // in-bucket clamp
            int src = GATHER ? rowidx[p] : p;
            ap[i] = Ab + (size_t)src * K + quad * 8;
        }

        floatx4 acc[FM][FN];
#pragma unroll
        for (int i = 0; i < FM; ++i)
#pragma unroll
            for (int j = 0; j < FN; ++j) acc[i][j] = floatx4{0.f, 0.f, 0.f, 0.f};

        short8 ab[DEPTH][FM], wb[DEPTH][FN];
        auto load = [&](int s, int buf) {
#pragma unroll
            for (int i = 0; i < FM; ++i)
                ab[buf][i] = *(const short8*)(ap[i] + s * 32);
#pragma unroll
            for (int j = 0; j < FN; ++j)
                wb[buf][j] = *(const short8*)(wp[j] + s * 32);
        };

#pragma unroll
        for (int pi = 0; pi < DEPTH - 1; ++pi) load(pi, pi);

        for (int s0 = 0; s0 < NS; s0 += DEPTH) {
#pragma unroll
            for (int u = 0; u < DEPTH; ++u) {
                const int s = s0 + u;
                if (s + DEPTH - 1 < NS)
                    load(s + DEPTH - 1, (u + DEPTH - 1) % DEPTH);
#pragma unroll
                for (int i = 0; i < FM; ++i)
#pragma unroll
                    for (int j = 0; j < FN; ++j)
                        acc[i][j] = __builtin_amdgcn_mfma_f32_16x16x32_bf16(
                            ab[u][i], wb[u][j], acc[i][j], 0, 0, 0);
            }
        }

        // epilogue: bias + relu; C layout col=lane&15, row=quad*4+reg
#pragma unroll
        for (int i = 0; i < FM; ++i) {
#pragma unroll
            for (int rg = 0; rg < 4; ++rg) {
                int m = i * 16 + quad * 4 + rg;
                int p = row_start + m;
                if (p < bend) {
                    if constexpr (SCATTER) {
                        int orow = rowidx[p];
#pragma unroll
                        for (int j = 0; j < FN; ++j) {
                            int n = n0 + j * 16 + lm;
                            float v = acc[i][j][rg] + bias[j];
                            OutF[(size_t)orow * N + n] = v > 0.f ? v : 0.f;
                        }
                    } else {
#pragma unroll
                        for (int j = 0; j < FN; ++j) {
                            int n = n0 + j * 16 + lm;
                            float v = acc[i][j][rg] + bias[j];
                            OutB[(size_t)p * N + n] = f2bf(v > 0.f ? v : 0.f);
                        }
                    }
                }
            }
        }
    }
}

extern "C" void kernel_launch(void* const* d_in, const int* in_sizes, int n_in,
                              void* d_out, int out_size, void* d_ws, size_t ws_size,
                              hipStream_t stream) {
    const float* x = (const float*)d_in[0];
    const int* ind = (const int*)d_in[1];
    const float* sk0 = (const float*)d_in[2];
    const float* sb0 = (const float*)d_in[3];
    const float* dk0 = (const float*)d_in[4];
    const float* db0 = (const float*)d_in[5];
    const float* sk1 = (const float*)d_in[6];
    const float* sb1 = (const float*)d_in[7];
    const float* dk1 = (const float*)d_in[8];
    const float* db1 = (const float*)d_in[9];
    const float* sk2 = (const float*)d_in[10];
    const float* sb2 = (const float*)d_in[11];
    const float* dk2 = (const float*)d_in[12];
    const float* db2 = (const float*)d_in[13];
    float* out = (float*)d_out;

    // workspace layout (~46 MB)
    char* ws = (char*)d_ws;
    int* offsets = (int*)ws;                                      // 64 B
    int* rowidx = (int*)(ws + 256);                               // 16 KB
    unsigned short* xb  = (unsigned short*)(ws + 32768);          // 8 MB  bf16 x, original order
    unsigned short* h1  = xb + (size_t)NROWS * 1024;              // 8 MB  bucket order
    unsigned short* h2  = h1 + (size_t)NROWS * 1024;              // 4 MB  bucket order
    unsigned short* w0t = h2 + (size_t)NROWS * 512;               // 16 MB [d][n=1024][k=1024]
    unsigned short* w1t = w0t + (size_t)NDOM * 1024 * 1024;       // 8 MB  [d][n=512][k=1024]
    unsigned short* w2t = w1t + (size_t)NDOM * 512 * 1024;        // 2 MB  [d][n=256][k=512]

    precompute_kernel<<<256 + 512 + 256 + 64 + 1, 256, 0, stream>>>(
        x, ind, sk0, dk0, sk1, dk1, sk2, dk2, xb, w0t, w1t, w2t, offsets, rowidx);

    // L0: 32x32 wave tiles, 8d x (16m x 32n = 512 waves) = 1024 blocks (16 waves/CU)
    star_gemm<2, 2, 16, 1024, 1024, true, false><<<1024, 256, 0, stream>>>(
        xb, w0t, sb0, db0, nullptr, h1, offsets, rowidx);
    // L1: 32x32 wave tiles, 8d x (16m x 16n = 256 waves) = 512 blocks (8 waves/CU)
    star_gemm<2, 2, 16, 1024, 512, false, false><<<512, 256, 0, stream>>>(
        h1, w1t, sb1, db1, nullptr, h2, offsets, rowidx);
    // L2: 32x32 wave tiles, 8d x (16m x 8n = 128 waves) = 256 blocks
    star_gemm<2, 2, 16, 512, 256, false, true><<<256, 256, 0, stream>>>(
        h2, w2t, sb2, db2, out, nullptr, offsets, rowidx);
}

// Round 9
// 288.882 us; speedup vs baseline: 1.2014x; 1.2014x over previous
//
#include <hip/hip_runtime.h>

#define NROWS 4096
#define NDOM 8

typedef short short8 __attribute__((ext_vector_type(8)));
typedef float floatx4 __attribute__((ext_vector_type(4)));
typedef unsigned short ushort8v __attribute__((ext_vector_type(8)));

__device__ __forceinline__ unsigned short f2bf(float f) {
    union { float f; unsigned u; } v; v.f = f;
    unsigned r = v.u + 0x7FFFu + ((v.u >> 16) & 1u);  // RNE
    return (unsigned short)(r >> 16);
}

// ---------------------------------------------------------------------------
// Fused precompute dispatch (unchanged from R8):
//   blocks [0,256)     : xb = bf16(x), original row order
//   blocks [256,768)   : w0t = bf16(sk0*dk0) transposed [d][n][k]
//   blocks [768,1024)  : w1t
//   blocks [1024,1088) : w2t
//   block 1088         : deterministic counting-sort -> offsets, rowidx
// ---------------------------------------------------------------------------

template <int K, int N>
__device__ __forceinline__ void weff_tile(const float* __restrict__ sk,
                                          const float* __restrict__ dk,
                                          unsigned short* __restrict__ wt,
                                          unsigned short* __restrict__ lds,
                                          int local) {
    const int d = local & 7;
    const int rest = local >> 3;
    const int k0 = (rest & (K / 256 - 1)) * 256;
    const int n0 = (rest / (K / 256)) * 64;
    const int t = threadIdx.x;

    const int q = t & 15;
    const int kr = t >> 4;
    const int ke = kr & 7;
#pragma unroll
    for (int pass = 0; pass < 16; ++pass) {
        const int krel = pass * 16 + kr;
        const int k = k0 + krel;
        floatx4 s = *(const floatx4*)(sk + (size_t)k * N + n0 + q * 4);
        floatx4 dd = *(const floatx4*)(dk + ((size_t)d * K + k) * N + n0 + q * 4);
        const int ch = krel >> 3;
#pragma unroll
        for (int c = 0; c < 4; ++c) {
            int n = q * 4 + c;
            lds[n * 256 + (ch ^ (n & 31)) * 8 + ke] = f2bf(s[c] * dd[c]);
        }
    }
    __syncthreads();

#pragma unroll
    for (int it = 0; it < 4; ++it) {
        const int nn = (t >> 4) + it * 16;
        const int c = t & 15;
        ushort8v a = *(ushort8v*)&lds[nn * 256 + ((2 * c) ^ (nn & 31)) * 8];
        ushort8v b = *(ushort8v*)&lds[nn * 256 + ((2 * c + 1) ^ (nn & 31)) * 8];
        unsigned short* dst = wt + ((size_t)d * N + n0 + nn) * K + k0 + c * 16;
        *(ushort8v*)dst = a;
        *(ushort8v*)(dst + 8) = b;
    }
}

__global__ void precompute_kernel(const float* __restrict__ x,
                                  const int* __restrict__ ind,
                                  const float* __restrict__ sk0, const float* __restrict__ dk0,
                                  const float* __restrict__ sk1, const float* __restrict__ dk1,
                                  const float* __restrict__ sk2, const float* __restrict__ dk2,
                                  unsigned short* __restrict__ xb,
                                  unsigned short* __restrict__ w0t,
                                  unsigned short* __restrict__ w1t,
                                  unsigned short* __restrict__ w2t,
                                  int* __restrict__ offsets,
                                  int* __restrict__ rowidx) {
    __shared__ unsigned short wtile[64 * 256];
    __shared__ unsigned short cnt[256][NDOM];
    __shared__ int base[256][NDOM];
    __shared__ int dom_total[NDOM];
    __shared__ int dom_off[NDOM + 1];

    const int b = blockIdx.x;
    const int t = threadIdx.x;

    if (b < 256) {
#pragma unroll
        for (int pass = 0; pass < 8; ++pass) {
            int row = b * 16 + pass * 2 + (t >> 7);
            int ch = t & 127;
            const float* src = x + (size_t)row * 1024 + ch * 8;
            floatx4 v0 = *(const floatx4*)src;
            floatx4 v1 = *(const floatx4*)(src + 4);
            unsigned short o[8];
            o[0] = f2bf(v0[0]); o[1] = f2bf(v0[1]); o[2] = f2bf(v0[2]); o[3] = f2bf(v0[3]);
            o[4] = f2bf(v1[0]); o[5] = f2bf(v1[1]); o[6] = f2bf(v1[2]); o[7] = f2bf(v1[3]);
            *(ushort8v*)(xb + (size_t)row * 1024 + ch * 8) = *(ushort8v*)o;
        }
    } else if (b < 256 + 512) {
        weff_tile<1024, 1024>(sk0, dk0, w0t, wtile, b - 256);
    } else if (b < 256 + 512 + 256) {
        weff_tile<1024, 512>(sk1, dk1, w1t, wtile, b - (256 + 512));
    } else if (b < 256 + 512 + 256 + 64) {
        weff_tile<512, 256>(sk2, dk2, w2t, wtile, b - (256 + 512 + 256));
    } else {
        int myind[16];
#pragma unroll
        for (int i = 0; i < 16; ++i) myind[i] = ind[t * 16 + i];
        unsigned short c[NDOM];
#pragma unroll
        for (int d = 0; d < NDOM; ++d) c[d] = 0;
#pragma unroll
        for (int i = 0; i < 16; ++i) c[myind[i]]++;
#pragma unroll
        for (int d = 0; d < NDOM; ++d) cnt[t][d] = c[d];
        __syncthreads();
        if (t < NDOM) {
            int acc = 0;
            for (int ch = 0; ch < 256; ++ch) { base[ch][t] = acc; acc += cnt[ch][t]; }
            dom_total[t] = acc;
        }
        __syncthreads();
        if (t == 0) {
            int acc = 0;
            for (int d = 0; d < NDOM; ++d) { dom_off[d] = acc; acc += dom_total[d]; }
            dom_off[NDOM] = acc;
        }
        __syncthreads();
        int pos[NDOM];
#pragma unroll
        for (int d = 0; d < NDOM; ++d) pos[d] = dom_off[d] + base[t][d];
#pragma unroll
        for (int i = 0; i < 16; ++i) {
            int dm = myind[i];
            rowidx[pos[dm]++] = t * 16 + i;
        }
        if (t <= NDOM) offsets[t] = dom_off[t];
    }
}

// ---------------------------------------------------------------------------
// Grouped GEMM, direct-to-register, no LDS, no barriers.
// Block = 4 waves arranged 2x2 over a 64x64 block tile; each wave computes an
// independent 32x32 register tile (acc 16 VGPR). Waves sharing a row-pair /
// col-pair issue identical A/W line addresses -> L1/L2 dedups (no barrier
// needed), halving L2-side traffic vs independent 32x32 tiles (R8).
// DEPTH=2 register double-buffer (32 VGPR) -> total demand ~85 VGPR:
// no spill (R8: forced 64 VGPR -> 180MB scratch; R7: 256 VGPR -> 1 wave/SIMD).
// ---------------------------------------------------------------------------
template <int MSLOTS, int K, int N, bool GATHER, bool SCATTER>
__launch_bounds__(256, 2)
__global__ void star_gemm(const unsigned short* __restrict__ Ab,
                          const unsigned short* __restrict__ Wt,
                          const float* __restrict__ sb,
                          const float* __restrict__ db,
                          float* __restrict__ OutF,
                          unsigned short* __restrict__ OutB,
                          const int* __restrict__ offsets,
                          const int* __restrict__ rowidx) {
    constexpr int NS = K / 32;                  // 32-wide k steps

    const int gid = blockIdx.x;
    const int w = threadIdx.x >> 6;
    const int lane = threadIdx.x & 63;
    const int lm = lane & 15;
    const int quad = lane >> 4;
    const int wm = w >> 1;                      // 2x2 wave grid over 64x64
    const int wn = w & 1;

    const int d = gid & 7;                      // domain -> XCD round-robin
    const int rest = gid >> 3;
    const int mslot = rest % MSLOTS;
    const int n0 = (rest / MSLOTS) * 64 + wn * 32;

    const int bstart = offsets[d];
    const int bend = offsets[d + 1];
    const int bsize = bend - bstart;

    float bias[2];
    const unsigned short* wp[2];
#pragma unroll
    for (int j = 0; j < 2; ++j) {
        int n = n0 + j * 16 + lm;
        bias[j] = sb[n] + db[d * N + n];
        wp[j] = Wt + ((size_t)d * N + n) * K + quad * 8;
    }

    for (int mt = mslot; mt * 64 < bsize; mt += MSLOTS) {
        const int row_start = bstart + mt * 64 + wm * 32;

        const unsigned short* ap[2];
#pragma unroll
        for (int i = 0; i < 2; ++i) {
            int p = row_start + i * 16 + lm;
            if (p >= bend) p = bend - 1;        // in-bucket clamp
            int src = GATHER ? rowidx[p] : p;
            ap[i] = Ab + (size_t)src * K + quad * 8;
        }

        floatx4 acc[2][2];
#pragma unroll
        for (int i = 0; i < 2; ++i)
#pragma unroll
            for (int j = 0; j < 2; ++j) acc[i][j] = floatx4{0.f, 0.f, 0.f, 0.f};

        short8 ab[2][2], wb[2][2];
        auto load = [&](int s, int buf) {
#pragma unroll
            for (int i = 0; i < 2; ++i)
                ab[buf][i] = *(const short8*)(ap[i] + s * 32);
#pragma unroll
            for (int j = 0; j < 2; ++j)
                wb[buf][j] = *(const short8*)(wp[j] + s * 32);
        };

        load(0, 0);
        for (int s = 0; s < NS; ++s) {          // dynamic loop: no mass hoisting
            const int buf = s & 1;
            if (s + 1 < NS) load(s + 1, 1 - buf);
#pragma unroll
            for (int i = 0; i < 2; ++i)
#pragma unroll
                for (int j = 0; j < 2; ++j)
                    acc[i][j] = __builtin_amdgcn_mfma_f32_16x16x32_bf16(
                        ab[buf][i], wb[buf][j], acc[i][j], 0, 0, 0);
        }

        // epilogue: bias + relu; C layout col=lane&15, row=quad*4+reg
#pragma unroll
        for (int i = 0; i < 2; ++i) {
#pragma unroll
            for (int rg = 0; rg < 4; ++rg) {
                int m = i * 16 + quad * 4 + rg;
                int p = row_start + m;
                if (p < bend) {
                    if constexpr (SCATTER) {
                        int orow = rowidx[p];
#pragma unroll
                        for (int j = 0; j < 2; ++j) {
                            int n = n0 + j * 16 + lm;
                            float v = acc[i][j][rg] + bias[j];
                            OutF[(size_t)orow * N + n] = v > 0.f ? v : 0.f;
                        }
                    } else {
#pragma unroll
                        for (int j = 0; j < 2; ++j) {
                            int n = n0 + j * 16 + lm;
                            float v = acc[i][j][rg] + bias[j];
                            OutB[(size_t)p * N + n] = f2bf(v > 0.f ? v : 0.f);
                        }
                    }
                }
            }
        }
    }
}

extern "C" void kernel_launch(void* const* d_in, const int* in_sizes, int n_in,
                              void* d_out, int out_size, void* d_ws, size_t ws_size,
                              hipStream_t stream) {
    const float* x = (const float*)d_in[0];
    const int* ind = (const int*)d_in[1];
    const float* sk0 = (const float*)d_in[2];
    const float* sb0 = (const float*)d_in[3];
    const float* dk0 = (const float*)d_in[4];
    const float* db0 = (const float*)d_in[5];
    const float* sk1 = (const float*)d_in[6];
    const float* sb1 = (const float*)d_in[7];
    const float* dk1 = (const float*)d_in[8];
    const float* db1 = (const float*)d_in[9];
    const float* sk2 = (const float*)d_in[10];
    const float* sb2 = (const float*)d_in[11];
    const float* dk2 = (const float*)d_in[12];
    const float* db2 = (const float*)d_in[13];
    float* out = (float*)d_out;

    // workspace layout (~46 MB)
    char* ws = (char*)d_ws;
    int* offsets = (int*)ws;                                      // 64 B
    int* rowidx = (int*)(ws + 256);                               // 16 KB
    unsigned short* xb  = (unsigned short*)(ws + 32768);          // 8 MB  bf16 x, original order
    unsigned short* h1  = xb + (size_t)NROWS * 1024;              // 8 MB  bucket order
    unsigned short* h2  = h1 + (size_t)NROWS * 1024;              // 4 MB  bucket order
    unsigned short* w0t = h2 + (size_t)NROWS * 512;               // 16 MB [d][n=1024][k=1024]
    unsigned short* w1t = w0t + (size_t)NDOM * 1024 * 1024;       // 8 MB  [d][n=512][k=1024]
    unsigned short* w2t = w1t + (size_t)NDOM * 512 * 1024;        // 2 MB  [d][n=256][k=512]

    precompute_kernel<<<256 + 512 + 256 + 64 + 1, 256, 0, stream>>>(
        x, ind, sk0, dk0, sk1, dk1, sk2, dk2, xb, w0t, w1t, w2t, offsets, rowidx);

    // L0: 64x64 block tiles, 8d x 8m x 16n = 1024 blocks (4/CU)
    star_gemm<8, 1024, 1024, true, false><<<1024, 256, 0, stream>>>(
        xb, w0t, sb0, db0, nullptr, h1, offsets, rowidx);
    // L1: 64x64 block tiles, 8d x 8m x 8n = 512 blocks
    star_gemm<8, 1024, 512, false, false><<<512, 256, 0, stream>>>(
        h1, w1t, sb1, db1, nullptr, h2, offsets, rowidx);
    // L2: 64x64 block tiles, 8d x 8m x 4n = 256 blocks (scatter to fp32 out)
    star_gemm<8, 512, 256, false, true><<<256, 256, 0, stream>>>(
        h2, w2t, sb2, db2, out, nullptr, offsets, rowidx);
}

// Round 10
// 197.017 us; speedup vs baseline: 1.7615x; 1.4663x over previous
//
#include <hip/hip_runtime.h>

#define NROWS 4096
#define NDOM 8

typedef short short8 __attribute__((ext_vector_type(8)));
typedef float floatx4 __attribute__((ext_vector_type(4)));
typedef unsigned short ushort8v __attribute__((ext_vector_type(8)));

__device__ __forceinline__ unsigned short f2bf(float f) {
    union { float f; unsigned u; } v; v.f = f;
    unsigned r = v.u + 0x7FFFu + ((v.u >> 16) & 1u);  // RNE
    return (unsigned short)(r >> 16);
}

// async global->LDS, 16B per lane; dest = wave-uniform base + lane*16
__device__ __forceinline__ void dma16(const void* g, void* l) {
    __builtin_amdgcn_global_load_lds(
        (const __attribute__((address_space(1))) unsigned*)g,
        (__attribute__((address_space(3))) unsigned*)l, 16, 0, 0);
}

// ---------------------------------------------------------------------------
// weff tile: one (domain, 64n, 256k) tile of w_eff^T = bf16(sk*dk) -> [d][n][k].
// Phase A reads float4 along n (coalesced), phase B stores k-contiguous 32B.
// ---------------------------------------------------------------------------
template <int K, int N>
__device__ __forceinline__ void weff_tile(const float* __restrict__ sk,
                                          const float* __restrict__ dk,
                                          unsigned short* __restrict__ wt,
                                          unsigned short* __restrict__ lds,
                                          int local) {
    const int d = local & 7;
    const int rest = local >> 3;
    const int k0 = (rest & (K / 256 - 1)) * 256;
    const int n0 = (rest / (K / 256)) * 64;
    const int t = threadIdx.x;

    const int q = t & 15;          // n-quad
    const int kr = t >> 4;         // k-row in group of 16
    const int ke = kr & 7;
#pragma unroll
    for (int pass = 0; pass < 16; ++pass) {
        const int krel = pass * 16 + kr;
        const int k = k0 + krel;
        floatx4 s = *(const floatx4*)(sk + (size_t)k * N + n0 + q * 4);
        floatx4 dd = *(const floatx4*)(dk + ((size_t)d * K + k) * N + n0 + q * 4);
        const int ch = krel >> 3;
#pragma unroll
        for (int c = 0; c < 4; ++c) {
            int n = q * 4 + c;
            lds[n * 256 + (ch ^ (n & 31)) * 8 + ke] = f2bf(s[c] * dd[c]);
        }
    }
    __syncthreads();

#pragma unroll
    for (int it = 0; it < 4; ++it) {
        const int nn = (t >> 4) + it * 16;
        const int c = t & 15;
        ushort8v a = *(ushort8v*)&lds[nn * 256 + ((2 * c) ^ (nn & 31)) * 8];
        ushort8v b = *(ushort8v*)&lds[nn * 256 + ((2 * c + 1) ^ (nn & 31)) * 8];
        unsigned short* dst = wt + ((size_t)d * N + n0 + nn) * K + k0 + c * 16;
        *(ushort8v*)dst = a;
        *(ushort8v*)(dst + 8) = b;
    }
}

// ---------------------------------------------------------------------------
// GEMM body (the 187.6-us structure, verbatim): double-buffered LDS DMA,
// one barrier per k-tile, frag reads hoisted before next DMA issue.
// Shared memory passed in (unioned with weff in the combo kernel).
// ---------------------------------------------------------------------------
template <int FM, int FN, int MSLOTS, int K, int N, bool GATHER, bool SCATTER>
__device__ __forceinline__ void gemm_body(char* smem, int gid,
                                          const unsigned short* __restrict__ Ab,
                                          const unsigned short* __restrict__ Wt,
                                          const float* __restrict__ sb,
                                          const float* __restrict__ db,
                                          float* __restrict__ OutF,
                                          unsigned short* __restrict__ OutB,
                                          const int* __restrict__ offsets,
                                          const int* __restrict__ rowidx) {
    constexpr int BM = 32 * FM;
    constexpr int BN = 32 * FN;
    constexpr int NK = K / 64;
    constexpr int AI = BM / 32;
    constexpr int WI = BN / 32;

    unsigned short* As = (unsigned short*)smem;      // 2 * BM*64
    unsigned short* Ws = As + 2 * BM * 64;           // 2 * BN*64

    const int d = gid & 7;                      // domain -> XCD round-robin
    const int mslot = (gid >> 3) % MSLOTS;
    const int n0 = ((gid >> 3) / MSLOTS) * BN;

    const int bstart = offsets[d];
    const int bend = offsets[d + 1];
    const int bsize = bend - bstart;

    const int tid = threadIdx.x;
    const int lane = tid & 63;
    const int w = tid >> 6;
    const int wy = w >> 1;
    const int wx = w & 1;
    const int lm = lane & 15;
    const int quad = lane >> 4;

    const int lrow = lane >> 3;
    const int phys = lane & 7;

    float bias[FN];
#pragma unroll
    for (int j = 0; j < FN; ++j) {
        int n = n0 + wx * FN * 16 + j * 16 + lm;
        bias[j] = sb[n] + db[d * N + n];
    }

    const unsigned short* wsrc[WI];
#pragma unroll
    for (int j = 0; j < WI; ++j) {
        int nr0 = (w * WI + j) * 8;
        int nn = nr0 + lrow;
        int ch = phys ^ (nn & 7);
        wsrc[j] = Wt + ((size_t)d * N + n0 + nn) * K + ch * 8;
    }

    for (int mt = mslot; mt * BM < bsize; mt += MSLOTS) {
        const int row_start = bstart + mt * BM;

        const unsigned short* asrc[AI];
#pragma unroll
        for (int j = 0; j < AI; ++j) {
            int m0 = (w * AI + j) * 8;
            int mm = m0 + lrow;
            int ch = phys ^ (mm & 7);
            int p = row_start + mm; if (p >= bend) p = bend - 1;
            int src = GATHER ? rowidx[p] : p;
            asrc[j] = Ab + (size_t)src * K + ch * 8;
        }

        auto dma_tiles = [&](int kt, int buf) {
            const int k0 = kt * 64;
#pragma unroll
            for (int j = 0; j < AI; ++j)
                dma16(asrc[j] + k0, As + buf * BM * 64 + (w * AI + j) * 512);
#pragma unroll
            for (int j = 0; j < WI; ++j)
                dma16(wsrc[j] + k0, Ws + buf * BN * 64 + (w * WI + j) * 512);
        };

        floatx4 acc[FM][FN];
#pragma unroll
        for (int i = 0; i < FM; ++i)
#pragma unroll
            for (int j = 0; j < FN; ++j) acc[i][j] = floatx4{0.f, 0.f, 0.f, 0.f};

        dma_tiles(0, 0);
        for (int kt = 0; kt < NK; ++kt) {
            const int buf = kt & 1;
            __syncthreads();                   // drains dma(kt); prev reads done

            short8 av[2][FM], wv[2][FN];
#pragma unroll
            for (int kk = 0; kk < 2; ++kk) {
#pragma unroll
                for (int i = 0; i < FM; ++i) {
                    int m = wy * FM * 16 + i * 16 + lm;
                    int pc = (kk * 4 + quad) ^ (m & 7);
                    av[kk][i] = *(const short8*)&As[buf * BM * 64 + m * 64 + pc * 8];
                }
#pragma unroll
                for (int j = 0; j < FN; ++j) {
                    int n = wx * FN * 16 + j * 16 + lm;
                    int pc = (kk * 4 + quad) ^ (n & 7);
                    wv[kk][j] = *(const short8*)&Ws[buf * BN * 64 + n * 64 + pc * 8];
                }
            }
            if (kt + 1 < NK) dma_tiles(kt + 1, 1 - buf);
#pragma unroll
            for (int kk = 0; kk < 2; ++kk)
#pragma unroll
                for (int i = 0; i < FM; ++i)
#pragma unroll
                    for (int j = 0; j < FN; ++j)
                        acc[i][j] = __builtin_amdgcn_mfma_f32_16x16x32_bf16(
                            av[kk][i], wv[kk][j], acc[i][j], 0, 0, 0);
        }

        // epilogue: bias + relu; C layout col=lane&15, row=quad*4+reg
#pragma unroll
        for (int i = 0; i < FM; ++i) {
#pragma unroll
            for (int rg = 0; rg < 4; ++rg) {
                int m = wy * FM * 16 + i * 16 + quad * 4 + rg;
                int p = row_start + m;
                if (p < bend) {
                    if constexpr (SCATTER) {
                        int orow = rowidx[p];
#pragma unroll
                        for (int j = 0; j < FN; ++j) {
                            int n = n0 + wx * FN * 16 + j * 16 + lm;
                            float v = acc[i][j][rg] + bias[j];
                            OutF[(size_t)orow * N + n] = v > 0.f ? v : 0.f;
                        }
                    } else {
#pragma unroll
                        for (int j = 0; j < FN; ++j) {
                            int n = n0 + wx * FN * 16 + j * 16 + lm;
                            float v = acc[i][j][rg] + bias[j];
                            OutB[(size_t)p * N + n] = f2bf(v > 0.f ? v : 0.f);
                        }
                    }
                }
            }
        }
    }
}

// ---------------------------------------------------------------------------
// pre0: blocks [0,256) xb=bf16(x); [256,768) w0t; block 768: counting sort
// ---------------------------------------------------------------------------
__global__ void pre0_kernel(const float* __restrict__ x,
                            const int* __restrict__ ind,
                            const float* __restrict__ sk0, const float* __restrict__ dk0,
                            unsigned short* __restrict__ xb,
                            unsigned short* __restrict__ w0t,
                            int* __restrict__ offsets,
                            int* __restrict__ rowidx) {
    __shared__ unsigned short wtile[64 * 256];
    __shared__ unsigned short cnt[256][NDOM];
    __shared__ int base[256][NDOM];
    __shared__ int dom_total[NDOM];
    __shared__ int dom_off[NDOM + 1];

    const int b = blockIdx.x;
    const int t = threadIdx.x;

    if (b < 256) {
#pragma unroll
        for (int pass = 0; pass < 8; ++pass) {
            int row = b * 16 + pass * 2 + (t >> 7);
            int ch = t & 127;
            const float* src = x + (size_t)row * 1024 + ch * 8;
            floatx4 v0 = *(const floatx4*)src;
            floatx4 v1 = *(const floatx4*)(src + 4);
            unsigned short o[8];
            o[0] = f2bf(v0[0]); o[1] = f2bf(v0[1]); o[2] = f2bf(v0[2]); o[3] = f2bf(v0[3]);
            o[4] = f2bf(v1[0]); o[5] = f2bf(v1[1]); o[6] = f2bf(v1[2]); o[7] = f2bf(v1[3]);
            *(ushort8v*)(xb + (size_t)row * 1024 + ch * 8) = *(ushort8v*)o;
        }
    } else if (b < 256 + 512) {
        weff_tile<1024, 1024>(sk0, dk0, w0t, wtile, b - 256);
    } else {
        // deterministic stable counting sort (pure function of ind)
        int myind[16];
#pragma unroll
        for (int i = 0; i < 16; ++i) myind[i] = ind[t * 16 + i];
        unsigned short c[NDOM];
#pragma unroll
        for (int d = 0; d < NDOM; ++d) c[d] = 0;
#pragma unroll
        for (int i = 0; i < 16; ++i) c[myind[i]]++;
#pragma unroll
        for (int d = 0; d < NDOM; ++d) cnt[t][d] = c[d];
        __syncthreads();
        if (t < NDOM) {
            int acc = 0;
            for (int ch = 0; ch < 256; ++ch) { base[ch][t] = acc; acc += cnt[ch][t]; }
            dom_total[t] = acc;
        }
        __syncthreads();
        if (t == 0) {
            int acc = 0;
            for (int d = 0; d < NDOM; ++d) { dom_off[d] = acc; acc += dom_total[d]; }
            dom_off[NDOM] = acc;
        }
        __syncthreads();
        int pos[NDOM];
#pragma unroll
        for (int d = 0; d < NDOM; ++d) pos[d] = dom_off[d] + base[t][d];
#pragma unroll
        for (int i = 0; i < 16; ++i) {
            int dm = myind[i];
            rowidx[pos[dm]++] = t * 16 + i;
        }
        if (t <= NDOM) offsets[t] = dom_off[t];
    }
}

// ---------------------------------------------------------------------------
// combo: blocks [0,512) L0 GEMM; [512,768) w1t; [768,832) w2t.
// w1t/w2t streaming hides under L0's latency-bound phase (independent data).
// ---------------------------------------------------------------------------
__launch_bounds__(256)
__global__ void combo_kernel(const unsigned short* __restrict__ xb,
                             const unsigned short* __restrict__ w0t,
                             const float* __restrict__ sb0, const float* __restrict__ db0,
                             unsigned short* __restrict__ h1,
                             const float* __restrict__ sk1, const float* __restrict__ dk1,
                             const float* __restrict__ sk2, const float* __restrict__ dk2,
                             unsigned short* __restrict__ w1t,
                             unsigned short* __restrict__ w2t,
                             const int* __restrict__ offsets,
                             const int* __restrict__ rowidx) {
    __shared__ __align__(16) char smem[49152];   // max(GEMM 48KB, weff 32KB)
    const int b = blockIdx.x;
    if (b < 512) {
        gemm_body<2, 4, 8, 1024, 1024, true, false>(
            smem, b, xb, w0t, sb0, db0, nullptr, h1, offsets, rowidx);
    } else if (b < 768) {
        weff_tile<1024, 512>(sk1, dk1, w1t, (unsigned short*)smem, b - 512);
    } else {
        weff_tile<512, 256>(sk2, dk2, w2t, (unsigned short*)smem, b - 768);
    }
}

template <int FM, int FN, int MSLOTS, int K, int N, bool GATHER, bool SCATTER>
__launch_bounds__(256)
__global__ void star_gemm(const unsigned short* __restrict__ Ab,
                          const unsigned short* __restrict__ Wt,
                          const float* __restrict__ sb,
                          const float* __restrict__ db,
                          float* __restrict__ OutF,
                          unsigned short* __restrict__ OutB,
                          const int* __restrict__ offsets,
                          const int* __restrict__ rowidx) {
    __shared__ __align__(16) char smem[(2 * FM * 32 * 64 + 2 * FN * 32 * 64) * 2];
    gemm_body<FM, FN, MSLOTS, K, N, GATHER, SCATTER>(
        smem, blockIdx.x, Ab, Wt, sb, db, OutF, OutB, offsets, rowidx);
}

extern "C" void kernel_launch(void* const* d_in, const int* in_sizes, int n_in,
                              void* d_out, int out_size, void* d_ws, size_t ws_size,
                              hipStream_t stream) {
    const float* x = (const float*)d_in[0];
    const int* ind = (const int*)d_in[1];
    const float* sk0 = (const float*)d_in[2];
    const float* sb0 = (const float*)d_in[3];
    const float* dk0 = (const float*)d_in[4];
    const float* db0 = (const float*)d_in[5];
    const float* sk1 = (const float*)d_in[6];
    const float* sb1 = (const float*)d_in[7];
    const float* dk1 = (const float*)d_in[8];
    const float* db1 = (const float*)d_in[9];
    const float* sk2 = (const float*)d_in[10];
    const float* sb2 = (const float*)d_in[11];
    const float* dk2 = (const float*)d_in[12];
    const float* db2 = (const float*)d_in[13];
    float* out = (float*)d_out;

    // workspace layout (~46 MB)
    char* ws = (char*)d_ws;
    int* offsets = (int*)ws;                                      // 64 B
    int* rowidx = (int*)(ws + 256);                               // 16 KB
    unsigned short* xb  = (unsigned short*)(ws + 32768);          // 8 MB  bf16 x, original order
    unsigned short* h1  = xb + (size_t)NROWS * 1024;              // 8 MB  bucket order
    unsigned short* h2  = h1 + (size_t)NROWS * 1024;              // 4 MB  bucket order
    unsigned short* w0t = h2 + (size_t)NROWS * 512;               // 16 MB [d][n=1024][k=1024]
    unsigned short* w1t = w0t + (size_t)NDOM * 1024 * 1024;       // 8 MB  [d][n=512][k=1024]
    unsigned short* w2t = w1t + (size_t)NDOM * 512 * 1024;        // 2 MB  [d][n=256][k=512]

    // pre0: xb (256) + w0t (512) + sort (1)
    pre0_kernel<<<769, 256, 0, stream>>>(x, ind, sk0, dk0, xb, w0t, offsets, rowidx);

    // combo: L0 GEMM 64x128 tiles (8d x 8m x 8n = 512) + w1t (256) + w2t (64)
    combo_kernel<<<832, 256, 0, stream>>>(xb, w0t, sb0, db0, h1,
                                          sk1, dk1, sk2, dk2, w1t, w2t,
                                          offsets, rowidx);

    // L1: 64x128 tiles, 8d x 8m x 4n = 256 blocks
    star_gemm<2, 4, 8, 1024, 512, false, false><<<256, 256, 0, stream>>>(
        h1, w1t, sb1, db1, nullptr, h2, offsets, rowidx);
    // L2: 32x64 tiles, 8d x 16m x 4n = 512 blocks (scatter to fp32 out)
    star_gemm<1, 2, 16, 512, 256, false, true><<<512, 256, 0, stream>>>(
        h2, w2t, sb2, db2, out, nullptr, offsets, rowidx);
}